// Round 3
// baseline (931.162 us; speedup 1.0000x reference)
//
#include <hip/hip_runtime.h>
#include <math.h>

// Problem constants (B=8, T=4096, H*D=512, C=64, K=8, CK=512, MODES=32, L=2)
constexpr int NB = 8;
constexpr int CKN = 512;
constexpr int NMODE = 32;
constexpr int NCH = 8;   // mode_mul i-chunks

typedef __attribute__((ext_vector_type(8))) short short8x;   // 8 bf16 (4 VGPRs)
typedef __attribute__((ext_vector_type(4))) float f32x4;     // 4 fp32 acc

__device__ inline unsigned short f2bf(float f) {
  union { float f; unsigned u; } v; v.f = f;
  unsigned u = v.u;
  unsigned r = (u + 0x7fffu + ((u >> 16) & 1u)) >> 16;   // RNE
  return (unsigned short)r;
}

// ---------------- bf16 MFMA GEMM: C[M,512] = A[M,512] @ W[512,512] + bias ----------------
__global__ __launch_bounds__(256) void gemm_mfma(
    const float* __restrict__ A, const float* __restrict__ W,
    const float* __restrict__ bias, float* __restrict__ C) {
  __shared__ __align__(16) unsigned short As[128 * 40];  // [m][k] k-contig, stride 40
  __shared__ __align__(16) unsigned short Bs[128 * 40];  // [n][k] k-contig (B^T), stride 40
  const int bm = blockIdx.x * 128, bn = blockIdx.y * 128;
  const int tid = threadIdx.x;
  const int wave = tid >> 6, lane = tid & 63;
  const int wm = (wave >> 1) * 64, wn = (wave & 1) * 64;
  const int lm = lane & 15, quad = lane >> 4;

  f32x4 zero = {0.f, 0.f, 0.f, 0.f};
  f32x4 acc[4][4];
#pragma unroll
  for (int i = 0; i < 4; ++i)
#pragma unroll
    for (int j = 0; j < 4; ++j) acc[i][j] = zero;

  for (int k0 = 0; k0 < 512; k0 += 32) {
    __syncthreads();
#pragma unroll
    for (int r = 0; r < 4; ++r) {
      int slot = tid + r * 256;
      int m = slot >> 3, k4 = (slot & 7) << 2;
      float4 v = *(const float4*)&A[(size_t)(bm + m) * 512 + k0 + k4];
      ushort4 u;
      u.x = f2bf(v.x); u.y = f2bf(v.y); u.z = f2bf(v.z); u.w = f2bf(v.w);
      *(ushort4*)&As[m * 40 + k4] = u;
    }
#pragma unroll
    for (int r = 0; r < 4; ++r) {
      int slot = tid + r * 256;
      int n = slot & 127, kg = slot >> 7;
      float w0 = W[(size_t)(k0 + kg * 4 + 0) * 512 + bn + n];
      float w1 = W[(size_t)(k0 + kg * 4 + 1) * 512 + bn + n];
      float w2 = W[(size_t)(k0 + kg * 4 + 2) * 512 + bn + n];
      float w3 = W[(size_t)(k0 + kg * 4 + 3) * 512 + bn + n];
      ushort4 u;
      u.x = f2bf(w0); u.y = f2bf(w1); u.z = f2bf(w2); u.w = f2bf(w3);
      *(ushort4*)&Bs[n * 40 + kg * 4] = u;
    }
    __syncthreads();
    short8x af[4], bf[4];
#pragma unroll
    for (int ti = 0; ti < 4; ++ti)
      af[ti] = *(short8x*)&As[(wm + ti * 16 + lm) * 40 + quad * 8];
#pragma unroll
    for (int tj = 0; tj < 4; ++tj)
      bf[tj] = *(short8x*)&Bs[(wn + tj * 16 + lm) * 40 + quad * 8];
#pragma unroll
    for (int ti = 0; ti < 4; ++ti)
#pragma unroll
      for (int tj = 0; tj < 4; ++tj)
        acc[ti][tj] = __builtin_amdgcn_mfma_f32_16x16x32_bf16(af[ti], bf[tj], acc[ti][tj], 0, 0, 0);
  }
  float bv[4];
#pragma unroll
  for (int tj = 0; tj < 4; ++tj) bv[tj] = bias[bn + wn + tj * 16 + lm];
#pragma unroll
  for (int ti = 0; ti < 4; ++ti)
#pragma unroll
    for (int tj = 0; tj < 4; ++tj)
#pragma unroll
      for (int r = 0; r < 4; ++r)
        C[(size_t)(bm + wm + ti * 16 + quad * 4 + r) * 512 + bn + wn + tj * 16 + lm] =
            acc[ti][tj][r] + bv[tj];
}

// ---------------- wavelet coef ----------------
__global__ __launch_bounds__(256) void coef_kernel(
    const float* __restrict__ cur, const float* __restrict__ ecd,
    const float* __restrict__ ecs, float* __restrict__ dcoef,
    float* __restrict__ scoef, int nhalf) {
  __shared__ float wd[128], ws2[128];
  int tid = threadIdx.x;
  if (tid < 128) { wd[tid] = ecd[tid]; ws2[tid] = ecs[tid]; }
  __syncthreads();
  size_t idx = (size_t)blockIdx.x * 256 + tid;
  int c = (int)(idx & 63);
  int t = (int)((idx >> 6) % (size_t)nhalf);
  int b = (int)(idx / ((size_t)nhalf * 64));
  const float* r0 = cur + ((size_t)b * nhalf * 2 + 2 * (size_t)t) * CKN + c * 8;
  float xa[16];
  *(float4*)&xa[0]  = *(const float4*)&r0[0];
  *(float4*)&xa[4]  = *(const float4*)&r0[4];
  *(float4*)&xa[8]  = *(const float4*)&r0[CKN];
  *(float4*)&xa[12] = *(const float4*)&r0[CKN + 4];
  float d[8] = {}, s[8] = {};
#pragma unroll
  for (int j = 0; j < 16; ++j) {
    float v = xa[j];
#pragma unroll
    for (int k = 0; k < 8; ++k) {
      d[k] += v * wd[j * 8 + k];
      s[k] += v * ws2[j * 8 + k];
    }
  }
  size_t o = ((size_t)b * nhalf + t) * CKN + c * 8;
  *(float4*)&dcoef[o]     = *(float4*)&d[0];
  *(float4*)&dcoef[o + 4] = *(float4*)&d[4];
  *(float4*)&scoef[o]     = *(float4*)&s[0];
  *(float4*)&scoef[o + 4] = *(float4*)&s[4];
}

// ---------------- forward truncated DFT: phasor recurrence, no LDS ----------------
// grid (P, NB, 8); block 256 = 32 x-modes x 8 ck-slots; lane owns (x, 8 ck), 64-t chunk
__global__ __launch_bounds__(256) void fwd_dft(
    const float* __restrict__ in, float* __restrict__ part, int n) {
  const int p = blockIdx.x, b = blockIdx.y, cb = blockIdx.z;
  const int P = gridDim.x;
  const int tid = threadIdx.x;
  const int cs = tid & 7, x = tid >> 3;
  const int ck = cb * 64 + cs * 8;
  const int t0 = p * 64;
  // phasor: e^{-2pi i x t / n}; init with exact integer phase reduction
  float c, s, cstep, sstep;
  float a0 = -6.28318530717958647692f * (float)((x * t0) % n) / (float)n;
  __sincosf(a0, &s, &c);
  float a1 = -6.28318530717958647692f * (float)x / (float)n;
  __sincosf(a1, &sstep, &cstep);
  float ar[8] = {}, ai[8] = {};
  const float* src = in + ((size_t)b * n + t0) * CKN + ck;
  for (int t = 0; t < 64; ++t) {
    float4 v0 = *(const float4*)&src[(size_t)t * CKN];
    float4 v1 = *(const float4*)&src[(size_t)t * CKN + 4];
    ar[0] += v0.x * c; ai[0] += v0.x * s;
    ar[1] += v0.y * c; ai[1] += v0.y * s;
    ar[2] += v0.z * c; ai[2] += v0.z * s;
    ar[3] += v0.w * c; ai[3] += v0.w * s;
    ar[4] += v1.x * c; ai[4] += v1.x * s;
    ar[5] += v1.y * c; ai[5] += v1.y * s;
    ar[6] += v1.z * c; ai[6] += v1.z * s;
    ar[7] += v1.w * c; ai[7] += v1.w * s;
    float cn = c * cstep - s * sstep;
    float sn = c * sstep + s * cstep;
    c = cn; s = sn;
  }
  float* pr = part + (((size_t)b * P + p) * NMODE + x) * CKN + ck;
  float* pi = pr + (size_t)NB * P * NMODE * CKN;
  *(float4*)&pr[0] = *(float4*)&ar[0];
  *(float4*)&pr[4] = *(float4*)&ar[4];
  *(float4*)&pi[0] = *(float4*)&ai[0];
  *(float4*)&pi[4] = *(float4*)&ai[4];
}

__global__ __launch_bounds__(256) void dft_reduce(
    const float* __restrict__ part, float* __restrict__ fre,
    float* __restrict__ fim, int P) {
  int idx = blockIdx.x * 256 + threadIdx.x;  // NB*32*512 = 131072
  int ck = idx & 511;
  int x = (idx >> 9) & 31;
  int b = idx >> 14;
  size_t base = ((size_t)b * P * NMODE + x) * CKN + ck;
  size_t ip = (size_t)NB * P * NMODE * CKN;
  size_t ps = (size_t)NMODE * CKN;
  float sr = 0.f, si = 0.f;
  for (int p = 0; p < P; ++p) { sr += part[base + p * ps]; si += part[base + ip + p * ps]; }
  fre[idx] = sr;
  fim[idx] = si;
}

// ---------------- per-mode complex channel-mix, both levels fused ----------------
// freq: 8 planes [lv2][pl4][b8][x32][i512]. Row-split across waves, o-block of 4.
// mpart[lv][ch8][b][x-inner layout: ((lv*8+ch)*8+b)*512+o)*32+x]*4comp
__global__ __launch_bounds__(256) void mode_mul(
    const float* __restrict__ freq,
    const float* __restrict__ wAre, const float* __restrict__ wAim,
    const float* __restrict__ wBre, const float* __restrict__ wBim,
    const float* __restrict__ wCre, const float* __restrict__ wCim,
    float* __restrict__ mpart) {
  __shared__ __align__(16) float lf[8192];   // [row16][comp4][x32][i4] = 32 KB
  const int otile = blockIdx.x, chunk = blockIdx.y;
  const int tid = threadIdx.x;
  const int wave = tid >> 6, lane = tid & 63;
  const int x = lane & 31, og = lane >> 5;
  const int r0 = wave * 4;
  const int i0 = chunk * 64;
  const int o0 = otile * 4 + og * 2;          // lane's o's: o0, o0+1
  const int sx = tid & 31, spl = (tid >> 5) & 3, srp = tid >> 7;
  float acc[4][2][4] = {};                     // [row][o][comp]
  for (int ii = 0; ii < 64; ii += 4) {
    __syncthreads();
#pragma unroll
    for (int j = 0; j < 8; ++j) {
      int row = srp * 8 + j;
      int lv = row >> 3, bb = row & 7;
      float4 v = *(const float4*)&freq[(size_t)(lv * 4 + spl) * 131072 +
                                       ((size_t)bb * 32 + sx) * 512 + i0 + ii];
      *(float4*)&lf[((row * 4 + spl) * 32 + sx) * 4] = v;
    }
    __syncthreads();
    float wv[4][2][6];
#pragma unroll
    for (int i = 0; i < 4; ++i)
#pragma unroll
      for (int o = 0; o < 2; ++o) {
        size_t wo = ((size_t)(i0 + ii + i) * 512 + (o0 + o)) * 32 + x;
        wv[i][o][0] = wAre[wo]; wv[i][o][1] = wAim[wo];
        wv[i][o][2] = wBre[wo]; wv[i][o][3] = wBim[wo];
        wv[i][o][4] = wCre[wo]; wv[i][o][5] = wCim[wo];
      }
#pragma unroll
    for (int r = 0; r < 4; ++r) {
      int row = r0 + r;
      float4 qdR = *(float4*)&lf[((row * 4 + 0) * 32 + x) * 4];
      float4 qdI = *(float4*)&lf[((row * 4 + 1) * 32 + x) * 4];
      float4 qsR = *(float4*)&lf[((row * 4 + 2) * 32 + x) * 4];
      float4 qsI = *(float4*)&lf[((row * 4 + 3) * 32 + x) * 4];
      const float* adR = (const float*)&qdR;
      const float* adI = (const float*)&qdI;
      const float* asR = (const float*)&qsR;
      const float* asI = (const float*)&qsI;
#pragma unroll
      for (int i = 0; i < 4; ++i) {
        float dR = adR[i], dI = adI[i], sR = asR[i], sI = asI[i];
#pragma unroll
        for (int o = 0; o < 2; ++o) {
          acc[r][o][0] += dR * wv[i][o][0] - dI * wv[i][o][1] + sR * wv[i][o][2] - sI * wv[i][o][3];
          acc[r][o][1] += dR * wv[i][o][1] + dI * wv[i][o][0] + sR * wv[i][o][3] + sI * wv[i][o][2];
          acc[r][o][2] += dR * wv[i][o][4] - dI * wv[i][o][5];
          acc[r][o][3] += dR * wv[i][o][5] + dI * wv[i][o][4];
        }
      }
    }
  }
#pragma unroll
  for (int r = 0; r < 4; ++r) {
    int row = r0 + r;
    int lv = row >> 3, bb = row & 7;
#pragma unroll
    for (int o = 0; o < 2; ++o) {
      float4 v;
      v.x = acc[r][o][0]; v.y = acc[r][o][1]; v.z = acc[r][o][2]; v.w = acc[r][o][3];
      *(float4*)&mpart[((((size_t)lv * NCH + chunk) * 8 + bb) * 512 + (o0 + o)) * 128 + (size_t)x * 4] = v;
    }
  }
}

__global__ __launch_bounds__(256) void mm_reduce(
    const float* __restrict__ mpart, float* __restrict__ outplanes) {
  int idx = blockIdx.x * 256 + threadIdx.x;  // 2*8*32*512 = 262144
  int x = idx & 31;
  int o = (idx >> 5) & 511;
  int b = (idx >> 14) & 7;
  int lvl = idx >> 17;
  float s0 = 0, s1 = 0, s2 = 0, s3 = 0;
  for (int ch = 0; ch < NCH; ++ch) {
    const float4 v = *(const float4*)&mpart[((((size_t)lvl * NCH + ch) * 8 + b) * 512 + o) * 128 + (size_t)x * 4];
    s0 += v.x; s1 += v.y; s2 += v.z; s3 += v.w;
  }
  size_t fo = ((size_t)b * 32 + x) * 512 + o;
  float* bp = outplanes + (size_t)lvl * 4 * 131072;
  bp[fo] = s0;
  bp[131072 + fo] = s1;
  bp[262144 + fo] = s2;
  bp[393216 + fo] = s3;
}

// ---------------- cur = cur @ t0_w + t0_b ----------------
__global__ __launch_bounds__(256) void t0_kernel(
    float* __restrict__ cur, const float* __restrict__ w,
    const float* __restrict__ bvec, int rows) {
  __shared__ float lw[64];
  __shared__ float lb[8];
  int tid = threadIdx.x;
  if (tid < 64) lw[tid] = w[tid];
  if (tid < 8) lb[tid] = bvec[tid];
  __syncthreads();
  size_t r = (size_t)blockIdx.x * 256 + tid;
  if (r >= (size_t)rows) return;
  float* p = cur + r * 8;
  float in[8];
  *(float4*)&in[0] = *(const float4*)&p[0];
  *(float4*)&in[4] = *(const float4*)&p[4];
  float outv[8];
#pragma unroll
  for (int k2 = 0; k2 < 8; ++k2) {
    float a = lb[k2];
#pragma unroll
    for (int k = 0; k < 8; ++k) a += in[k] * lw[k * 8 + k2];
    outv[k2] = a;
  }
  *(float4*)&p[0] = *(float4*)&outv[0];
  *(float4*)&p[4] = *(float4*)&outv[4];
}

// ---------------- truncated inverse rDFT: phasor recurrence, no LDS ----------------
// grid (n/64, NB, 2); lane owns 1 ck with fr/fi[32] in regs, 2 independent t-chains.
__global__ __launch_bounds__(256) void inv_dft(
    const float* __restrict__ fre, const float* __restrict__ fim,
    float* __restrict__ out, int n, int beta) {
  const int tb = blockIdx.x, b = blockIdx.y, chh = blockIdx.z;
  const int ck = chh * 256 + threadIdx.x;
  const float invn = 1.0f / (float)n;
  float fr[NMODE], fi[NMODE];
  const float* pr = fre + (size_t)b * NMODE * CKN + ck;
  const float* pi = fim + (size_t)b * NMODE * CKN + ck;
#pragma unroll
  for (int xx = 0; xx < NMODE; ++xx) {
    float w = (xx == 0) ? invn : 2.0f * invn;
    fr[xx] = pr[(size_t)xx * CKN] * w;
    fi[xx] = pi[(size_t)xx * CKN] * w;
  }
  float* dst = out + ((size_t)b * n + (size_t)tb * 64) * CKN + ck;
  for (int tt = 0; tt < 32; ++tt) {
    int ta = tb * 64 + tt;
    int tb2 = ta + 32;
    // chain phasors: e^{+2pi i t x / n}, step in x
    float cA, sA, c1A, s1A, cB, sB, c1B, s1B;
    __sincosf(6.28318530717958647692f * (float)ta / (float)n, &s1A, &c1A);
    __sincosf(6.28318530717958647692f * (float)tb2 / (float)n, &s1B, &c1B);
    cA = 1.f; sA = 0.f; cB = 1.f; sB = 0.f;
    float yA = 0.f, yB = 0.f;
#pragma unroll
    for (int xx = 0; xx < NMODE; ++xx) {
      yA += fr[xx] * cA - fi[xx] * sA;
      yB += fr[xx] * cB - fi[xx] * sB;
      float cnA = cA * c1A - sA * s1A;
      float snA = cA * s1A + sA * c1A;
      cA = cnA; sA = snA;
      float cnB = cB * c1B - sB * s1B;
      float snB = cB * s1B + sB * c1B;
      cB = cnB; sB = snB;
    }
    if (beta) {
      dst[(size_t)tt * CKN] += yA;
      dst[(size_t)(tt + 32) * CKN] += yB;
    } else {
      dst[(size_t)tt * CKN] = yA;
      dst[(size_t)(tt + 32) * CKN] = yB;
    }
  }
}

// ---------------- reconstruction ----------------
__global__ __launch_bounds__(256) void recon_kernel(
    const float* __restrict__ cur, const float* __restrict__ ud,
    const float* __restrict__ rce, const float* __restrict__ rco,
    float* __restrict__ out, int n) {
  __shared__ float we[128], wo[128];
  int tid = threadIdx.x;
  if (tid < 128) { we[tid] = rce[tid]; wo[tid] = rco[tid]; }
  __syncthreads();
  size_t idx = (size_t)blockIdx.x * 256 + tid;
  int c = (int)(idx & 63);
  int t = (int)((idx >> 6) % (size_t)n);
  int b = (int)(idx / ((size_t)n * 64));
  size_t off = ((size_t)b * n + t) * CKN + c * 8;
  float cat[16];
  *(float4*)&cat[0]  = *(const float4*)&cur[off];
  *(float4*)&cat[4]  = *(const float4*)&cur[off + 4];
  *(float4*)&cat[8]  = *(const float4*)&ud[off];
  *(float4*)&cat[12] = *(const float4*)&ud[off + 4];
  float xe[8] = {}, xo[8] = {};
#pragma unroll
  for (int j = 0; j < 16; ++j) {
    float v = cat[j];
#pragma unroll
    for (int k = 0; k < 8; ++k) {
      xe[k] += v * we[j * 8 + k];
      xo[k] += v * wo[j * 8 + k];
    }
  }
  size_t po = ((size_t)b * 2 * n + 2 * (size_t)t) * CKN + c * 8;
  *(float4*)&out[po]           = *(float4*)&xe[0];
  *(float4*)&out[po + 4]       = *(float4*)&xe[4];
  *(float4*)&out[po + CKN]     = *(float4*)&xo[0];
  *(float4*)&out[po + CKN + 4] = *(float4*)&xo[4];
}

extern "C" void kernel_launch(void* const* d_in, const int* in_sizes, int n_in,
                              void* d_out, int out_size, void* d_ws, size_t ws_size,
                              hipStream_t stream) {
  (void)in_sizes; (void)n_in; (void)out_size; (void)ws_size;
  const float* x         = (const float*)d_in[0];
  const float* lin_in_w  = (const float*)d_in[1];
  const float* lin_in_b  = (const float*)d_in[2];
  const float* lin_out_w = (const float*)d_in[3];
  const float* lin_out_b = (const float*)d_in[4];
  const float* t0_w      = (const float*)d_in[5];
  const float* t0_b      = (const float*)d_in[6];
  const float* wAre      = (const float*)d_in[7];
  const float* wAim      = (const float*)d_in[8];
  const float* wBre      = (const float*)d_in[9];
  const float* wBim      = (const float*)d_in[10];
  const float* wCre      = (const float*)d_in[11];
  const float* wCim      = (const float*)d_in[12];
  const float* ec_s      = (const float*)d_in[13];
  const float* ec_d      = (const float*)d_in[14];
  const float* rc_e      = (const float*)d_in[15];
  const float* rc_o      = (const float*)d_in[16];
  float* ws = (float*)d_ws;
  float* out = (float*)d_out;

  // workspace layout (floats)
  float* Z    = ws + 0;          // 16,777,216  (z / final cur; PART & MMP overlay)
  float* D0   = ws + 16777216;   //  8,388,608  (dcoef0, later Ud0)
  float* S0   = ws + 25165824;   //  8,388,608  (scoef0, later level-0 recon cur)
  float* D1   = ws + 33554432;   //  4,194,304  (dcoef1, later Ud1)
  float* S1   = ws + 37748736;   //  4,194,304  (scoef1 / cur1)
  float* F0   = ws + 41943040;   // 16 planes x 131,072
  float* PART = Z;               // DFT partials overlay
  float* MMP  = Z;               // mode-mul partials overlay

  // z = x @ lin_in_w + b   (bf16 MFMA)
  gemm_mfma<<<dim3(256, 4), 256, 0, stream>>>(x, lin_in_w, lin_in_b, Z);

  // level 0: n=4096 -> 2048 coefs
  coef_kernel<<<(NB * 2048 * 64) / 256, 256, 0, stream>>>(Z, ec_d, ec_s, D0, S0, 2048);

  fwd_dft<<<dim3(32, NB, 8), 256, 0, stream>>>(D0, PART, 2048);
  dft_reduce<<<512, 256, 0, stream>>>(PART, F0 + 0 * 131072, F0 + 1 * 131072, 32);
  fwd_dft<<<dim3(32, NB, 8), 256, 0, stream>>>(S0, PART, 2048);
  dft_reduce<<<512, 256, 0, stream>>>(PART, F0 + 2 * 131072, F0 + 3 * 131072, 32);

  // level 1: n=2048 -> 1024 coefs
  coef_kernel<<<(NB * 1024 * 64) / 256, 256, 0, stream>>>(S0, ec_d, ec_s, D1, S1, 1024);

  fwd_dft<<<dim3(16, NB, 8), 256, 0, stream>>>(D1, PART, 1024);
  dft_reduce<<<512, 256, 0, stream>>>(PART, F0 + 4 * 131072, F0 + 5 * 131072, 16);
  fwd_dft<<<dim3(16, NB, 8), 256, 0, stream>>>(S1, PART, 1024);
  dft_reduce<<<512, 256, 0, stream>>>(PART, F0 + 6 * 131072, F0 + 7 * 131072, 16);

  // spectral channel mix, both levels fused (single pass over 201MB of weights)
  mode_mul<<<dim3(128, NCH), 256, 0, stream>>>(F0, wAre, wAim, wBre, wBim, wCre, wCim, MMP);
  mm_reduce<<<1024, 256, 0, stream>>>(MMP, F0 + 8 * 131072);

  // cur = scoef1 @ t0_w + t0_b
  t0_kernel<<<(NB * 1024 * 64) / 256, 256, 0, stream>>>(S1, t0_w, t0_b, NB * 1024 * 64);

  // level 1 inverse + reconstruction -> S0 (n=2048)
  inv_dft<<<dim3(16, NB, 2), 256, 0, stream>>>(F0 + 14 * 131072, F0 + 15 * 131072, S1, 1024, 1);
  inv_dft<<<dim3(16, NB, 2), 256, 0, stream>>>(F0 + 12 * 131072, F0 + 13 * 131072, D1, 1024, 0);
  recon_kernel<<<(NB * 1024 * 64) / 256, 256, 0, stream>>>(S1, D1, rc_e, rc_o, S0, 1024);

  // level 0 inverse + reconstruction -> Z (n=4096)
  inv_dft<<<dim3(32, NB, 2), 256, 0, stream>>>(F0 + 10 * 131072, F0 + 11 * 131072, S0, 2048, 1);
  inv_dft<<<dim3(32, NB, 2), 256, 0, stream>>>(F0 + 8 * 131072, F0 + 9 * 131072, D0, 2048, 0);
  recon_kernel<<<(NB * 2048 * 64) / 256, 256, 0, stream>>>(S0, D0, rc_e, rc_o, Z, 2048);

  // out = cur @ lin_out_w + b   (bf16 MFMA)
  gemm_mfma<<<dim3(256, 4), 256, 0, stream>>>(Z, lin_out_w, lin_out_b, out);
}